// Round 1
// baseline (359.669 us; speedup 1.0000x reference)
//
#include <hip/hip_runtime.h>

// GeneModelClassic: B=32, G=18000, K=50, L=16
//   xs = x*scale_w + scale_b                (B, 900000)
//   xg = xs[:, snp_index]  -> (B, G, K)     (honored via real indexed loads)
//   out = relu(einsum('bgk,gkl->bgl', xg, W) + b).reshape(B, G*L)
//
// One wave per gene: lane = (b = lane&31, l-half = lane>>5); each lane holds
// 8 f32 accumulators. Memory-bound (~222 MB at ~6.3 TB/s => ~35 us floor).

#define B_ 32
#define G_ 18000
#define K_ 50
#define L_ 16
#define NS_ (G_ * K_)     // 900000
#define GPB 4             // genes (waves) per block
#define THREADS_ (GPB * 64)

__global__ __launch_bounds__(THREADS_, 2)
void gene_model_kernel(const float* __restrict__ x,
                       const float* __restrict__ sw,
                       const float* __restrict__ sb,
                       const float* __restrict__ W,
                       const float* __restrict__ bias,
                       const int*   __restrict__ sidx,
                       float*       __restrict__ out) {
  // wave index made provably uniform so idx/scale loads scalarize
  const int wave = __builtin_amdgcn_readfirstlane((int)(threadIdx.x >> 6));
  const int lane = (int)(threadIdx.x & 63);
  const int g    = (int)blockIdx.x * GPB + wave;
  const int b    = lane & 31;
  const int l0   = (lane >> 5) * 8;   // 0 or 8

  const float* __restrict__ Wg   = W + (size_t)g * (K_ * L_) + l0;
  const float* __restrict__ xrow = x + (size_t)b * NS_;
  const int*   __restrict__ idxg = sidx + g * K_;

  float acc[8];
  {
    const float4 bv0 = *reinterpret_cast<const float4*>(bias + (size_t)g * L_ + l0);
    const float4 bv1 = *reinterpret_cast<const float4*>(bias + (size_t)g * L_ + l0 + 4);
    acc[0] = bv0.x; acc[1] = bv0.y; acc[2] = bv0.z; acc[3] = bv0.w;
    acc[4] = bv1.x; acc[5] = bv1.y; acc[6] = bv1.z; acc[7] = bv1.w;
  }

#pragma unroll 5
  for (int k = 0; k < K_; ++k) {
    const int   idx = idxg[k];                          // wave-uniform -> s_load
    const float xs  = fmaf(xrow[idx], sw[idx], sb[idx]); // sw/sb uniform too
    const float4 w0 = *reinterpret_cast<const float4*>(Wg + k * L_);
    const float4 w1 = *reinterpret_cast<const float4*>(Wg + k * L_ + 4);
    acc[0] = fmaf(xs, w0.x, acc[0]);
    acc[1] = fmaf(xs, w0.y, acc[1]);
    acc[2] = fmaf(xs, w0.z, acc[2]);
    acc[3] = fmaf(xs, w0.w, acc[3]);
    acc[4] = fmaf(xs, w1.x, acc[4]);
    acc[5] = fmaf(xs, w1.y, acc[5]);
    acc[6] = fmaf(xs, w1.z, acc[6]);
    acc[7] = fmaf(xs, w1.w, acc[7]);
  }

  float4 o0, o1;
  o0.x = fmaxf(acc[0], 0.f); o0.y = fmaxf(acc[1], 0.f);
  o0.z = fmaxf(acc[2], 0.f); o0.w = fmaxf(acc[3], 0.f);
  o1.x = fmaxf(acc[4], 0.f); o1.y = fmaxf(acc[5], 0.f);
  o1.z = fmaxf(acc[6], 0.f); o1.w = fmaxf(acc[7], 0.f);

  float* op = out + (size_t)b * (G_ * L_) + (size_t)g * L_ + l0;
  *reinterpret_cast<float4*>(op)     = o0;
  *reinterpret_cast<float4*>(op + 4) = o1;
}

extern "C" void kernel_launch(void* const* d_in, const int* in_sizes, int n_in,
                              void* d_out, int out_size, void* d_ws, size_t ws_size,
                              hipStream_t stream) {
  const float* x    = (const float*)d_in[0];
  const float* sw   = (const float*)d_in[1];
  const float* sb   = (const float*)d_in[2];
  const float* W    = (const float*)d_in[3];
  const float* bias = (const float*)d_in[4];
  const int*   sidx = (const int*)d_in[5];
  float*       out  = (float*)d_out;

  dim3 grid(G_ / GPB);     // 4500 blocks, one wave per gene
  dim3 block(THREADS_);    // 256 threads = 4 waves
  gene_model_kernel<<<grid, block, 0, stream>>>(x, sw, sb, W, bias, sidx, out);
}

// Round 2
// 291.708 us; speedup vs baseline: 1.2330x; 1.2330x over previous
//
#include <hip/hip_runtime.h>

// GeneModelClassic: B=32, G=18000, K=50, L=16
//   out[b,g,l] = relu( sum_k (x[b,idx[g,k]]*sw[idx]+sb[idx]) * W[g,k,l] + bias[g,l] )
//
// R2: LDS-staged xs tile (4 genes/block), all global accesses coalesced.
// R1 was latency-bound: per-wave x gather spanned 32 cache lines/instruction.

#define B_ 32
#define G_ 18000
#define K_ 50
#define L_ 16
#define NS_ (G_ * K_)        // 900000
#define GT 4                 // genes per block
#define COLS (GT * K_)       // 200
#define Q_ (COLS / 4)        // 50 float4 per row
#define XS_STRIDE 204        // floats; 16B-aligned rows, bank-advance 12 -> <=4-way read conflict
#define THREADS_ 256

__global__ __launch_bounds__(THREADS_, 4)
void gene_model_kernel(const float* __restrict__ x,
                       const float* __restrict__ sw,
                       const float* __restrict__ sb,
                       const float* __restrict__ W,
                       const float* __restrict__ bias,
                       const int*   __restrict__ sidx,
                       float*       __restrict__ out) {
  __shared__ float xs_lds[B_ * XS_STRIDE];   // 26112 B
  __shared__ float swc[COLS];
  __shared__ float sbc[COLS];
  __shared__ int   idxc[COLS];

  const int tid = (int)threadIdx.x;
  const int g0  = (int)blockIdx.x * GT;

  // ---- phase 0: per-column index + scales (coalesced, once per block) ----
  if (tid < COLS) {
    const int idx = sidx[g0 * K_ + tid];
    idxc[tid] = idx;
    swc[tid]  = sw[idx];
    sbc[tid]  = sb[idx];
  }
  __syncthreads();

  // ---- phase 1: stage scaled xs tile (32 rows x 200 cols) into LDS ----
  for (int i = tid; i < B_ * Q_; i += THREADS_) {        // 1600 float4 slots
    const int r  = i / Q_;
    const int c4 = (i - r * Q_) * 4;
    const float* __restrict__ xr = x + (size_t)r * NS_;
    const int4   iv = *reinterpret_cast<const int4*>(&idxc[c4]);   // contiguous LDS reads
    const float4 sv = *reinterpret_cast<const float4*>(&swc[c4]);
    const float4 bv = *reinterpret_cast<const float4*>(&sbc[c4]);
    float4 v;
    v.x = fmaf(xr[iv.x], sv.x, bv.x);
    v.y = fmaf(xr[iv.y], sv.y, bv.y);
    v.z = fmaf(xr[iv.z], sv.z, bv.z);
    v.w = fmaf(xr[iv.w], sv.w, bv.w);
    *reinterpret_cast<float4*>(&xs_lds[r * XS_STRIDE + c4]) = v;
  }
  __syncthreads();

  // ---- phase 2: one wave per gene ----
  const int wave = __builtin_amdgcn_readfirstlane(tid >> 6);  // 0..3, uniform
  const int lane = tid & 63;
  const int g    = g0 + wave;
  const int b    = lane & 31;
  const int l0   = (lane >> 5) * 8;                           // 0 or 8

  const float* __restrict__ Wg  = W + (size_t)g * (K_ * L_) + l0;
  const float* __restrict__ xsp = &xs_lds[b * XS_STRIDE + wave * K_];

  float acc[8];
  {
    const float4 bv0 = *reinterpret_cast<const float4*>(bias + (size_t)g * L_ + l0);
    const float4 bv1 = *reinterpret_cast<const float4*>(bias + (size_t)g * L_ + l0 + 4);
    acc[0] = bv0.x; acc[1] = bv0.y; acc[2] = bv0.z; acc[3] = bv0.w;
    acc[4] = bv1.x; acc[5] = bv1.y; acc[6] = bv1.z; acc[7] = bv1.w;
  }

#pragma unroll 5
  for (int k = 0; k < K_; ++k) {
    const float  xv = xsp[k];
    const float4 w0 = *reinterpret_cast<const float4*>(Wg + k * L_);
    const float4 w1 = *reinterpret_cast<const float4*>(Wg + k * L_ + 4);
    acc[0] = fmaf(xv, w0.x, acc[0]);
    acc[1] = fmaf(xv, w0.y, acc[1]);
    acc[2] = fmaf(xv, w0.z, acc[2]);
    acc[3] = fmaf(xv, w0.w, acc[3]);
    acc[4] = fmaf(xv, w1.x, acc[4]);
    acc[5] = fmaf(xv, w1.y, acc[5]);
    acc[6] = fmaf(xv, w1.z, acc[6]);
    acc[7] = fmaf(xv, w1.w, acc[7]);
  }

  float4 o0, o1;
  o0.x = fmaxf(acc[0], 0.f); o0.y = fmaxf(acc[1], 0.f);
  o0.z = fmaxf(acc[2], 0.f); o0.w = fmaxf(acc[3], 0.f);
  o1.x = fmaxf(acc[4], 0.f); o1.y = fmaxf(acc[5], 0.f);
  o1.z = fmaxf(acc[6], 0.f); o1.w = fmaxf(acc[7], 0.f);

  float* op = out + (size_t)b * (G_ * L_) + (size_t)g * L_ + l0;
  *reinterpret_cast<float4*>(op)     = o0;
  *reinterpret_cast<float4*>(op + 4) = o1;
}

extern "C" void kernel_launch(void* const* d_in, const int* in_sizes, int n_in,
                              void* d_out, int out_size, void* d_ws, size_t ws_size,
                              hipStream_t stream) {
  const float* x    = (const float*)d_in[0];
  const float* sw   = (const float*)d_in[1];
  const float* sb   = (const float*)d_in[2];
  const float* W    = (const float*)d_in[3];
  const float* bias = (const float*)d_in[4];
  const int*   sidx = (const int*)d_in[5];
  float*       out  = (float*)d_out;

  dim3 grid(G_ / GT);      // 4500 blocks
  dim3 block(THREADS_);    // 256 threads = 4 waves
  gene_model_kernel<<<grid, block, 0, stream>>>(x, sw, sb, W, bias, sidx, out);
}